// Round 6
// baseline (291.650 us; speedup 1.0000x reference)
//
#include <hip/hip_runtime.h>
#include <cstdint>

#define GNY 1024
#define GNX 2048
#define GNPTS (GNY * GNX)

namespace {
constexpr float DT = 0.1f;
constexpr float NUc = 0.01f;
constexpr float INV_DIAG = -0.375f;   // 1/DIAG, DIAG = -8/(3*dx^2) = -8/3
}

// ---- boundary-condition index maps (verified against JAX .at[].set order) ----
__device__ __forceinline__ float bc_u_at(const float* __restrict__ f, int y, int x) {
    if (y < 0 || y >= GNY || x < 0) return 1.0f;
    if (x >= GNX) x = GNX - 1;
    return f[y * GNX + x];
}
__device__ __forceinline__ float bc_v_at(const float* __restrict__ f, int y, int x) {
    if (y < 0 || y >= GNY || x < 0) return 0.0f;
    if (x >= GNX) x = GNX - 1;
    return f[y * GNX + x];
}
__device__ __forceinline__ float bc_p_at(const float* __restrict__ f, int y, int x) {
    if (x >= GNX) return 0.0f;          // right ghost = 0 (dominates corners)
    if (x < 0) x = 0;
    y = min(max(y, 0), GNY - 1);
    return f[y * GNX + x];
}

// ---- stencils (cross-correlation, m[dy][dx] = f(y+dy-1, x+dx-1)) ----
__device__ __forceinline__ float conv_x3(const float m[3][3]) {
    return ((m[0][2] - m[0][0]) + 4.0f * (m[1][2] - m[1][0]) + (m[2][2] - m[2][0])) * (1.0f / 12.0f);
}
__device__ __forceinline__ float conv_y3(const float m[3][3]) {
    return ((m[2][0] - m[0][0]) + 4.0f * (m[2][1] - m[0][1]) + (m[2][2] - m[0][2])) * (1.0f / 12.0f);
}
__device__ __forceinline__ float conv_d3(const float m[3][3]) {
    return (m[0][0] + m[0][1] + m[0][2] + m[1][0] + m[1][2] + m[2][0] + m[2][1] + m[2][2]
            - 8.0f * m[1][1]) * (1.0f / 3.0f);
}

// up-step value: a(y,x) = P(par)(y,x) - conv(bc0(P(par)))/DIAG + r/DIAG at level (H,W)
template <typename PG>
__device__ __forceinline__ float up_val(PG pget, float rval, int H, int W, int y, int x) {
    float m[3][3];
#pragma unroll
    for (int dy = 0; dy < 3; ++dy)
#pragma unroll
        for (int dx = 0; dx < 3; ++dx) {
            int yy = y + dy - 1, xx = x + dx - 1;
            m[dy][dx] = (yy >= 0 && yy < H && xx >= 0 && xx < W) ? pget(yy >> 1, xx >> 1) : 0.0f;
        }
    float conv = (m[0][0] + m[0][1] + m[0][2] + m[1][0] + m[1][2]
                  + m[2][0] + m[2][1] + m[2][2] - 8.0f * m[1][1]) * (1.0f / 3.0f);
    return m[1][1] - conv * INV_DIAG + rval * INV_DIAG;
}

// ---- FUSED front-end with bc-mapped LDS staging; ALL global reads up front ----
__global__ __launch_bounds__(256) void k_front(
        const float* __restrict__ u, const float* __restrict__ v,
        const float* __restrict__ p, const float* __restrict__ sigma,
        float* __restrict__ u2g, float* __restrict__ v2g, float* __restrict__ bg,
        float* __restrict__ r1, float* __restrict__ r2, float* __restrict__ r3,
        float* __restrict__ r4, float* __restrict__ r5) {
    __shared__ float scrF[8442];
    float* sP    = scrF;              // 38x38 stride 39 (1482), origin (y0-3,x0-3), persists
    float* sU    = scrF + 1482;       // phase A (1482)
    float* sV    = scrF + 2964;       // phase A (1482)
    float* sU2   = scrF + 1482;       // phase B overlay, 34x35 (1190), origin (y0-1,x0-1)
    float* sV2   = scrF + 2672;       // (1190)
    float* sBu   = scrF + 4446;       // 36x37 (1332), origin (y0-2,x0-2)
    float* sBv   = scrF + 5778;       // (1332)
    float* sDamp = scrF + 7110;       // (1332) staged up front
    float* s0    = scrF + 4446;       // phase C overlay: 32x33 (1056)
    float* s1    = scrF + 5502;       // 16x17 (272)
    float* s2    = scrF + 5774;       // 8x9 (72)
    float* s3    = scrF + 5846;       // 4x5 (20)
    float* s4    = scrF + 5866;       // 2x3 (6)

    int t = threadIdx.x;
    int bx = blockIdx.x, by = blockIdx.y;
    int y0 = by * 32, x0 = bx * 32;
    bool edge = !(bx >= 1 && bx <= 62 && by >= 1 && by <= 30);
    bool rightcol = (bx == 63);

    // ---- burst staging: u/v/p (38x38 bc-mapped) + damp (36x36) ----
    if (!edge) {
        for (int i = t; i < 1444; i += 256) {
            int wy = i / 38, wx = i - wy * 38;
            int idx = (y0 - 3 + wy) * GNX + (x0 - 3 + wx);
            sP[wy * 39 + wx] = p[idx];
            sU[wy * 39 + wx] = u[idx];
            sV[wy * 39 + wx] = v[idx];
        }
        for (int i = t; i < 1296; i += 256) {
            int ay = i / 36, ax = i - ay * 36;
            sDamp[ay * 37 + ax] = 1.0f / (1.0f + DT * sigma[(y0 - 2 + ay) * GNX + x0 - 2 + ax]);
        }
    } else {
        for (int i = t; i < 1444; i += 256) {
            int wy = i / 38, wx = i - wy * 38;
            int gy = y0 - 3 + wy, gx = x0 - 3 + wx;
            sP[wy * 39 + wx] = bc_p_at(p, gy, gx);
            sU[wy * 39 + wx] = bc_u_at(u, gy, gx);
            sV[wy * 39 + wx] = bc_v_at(v, gy, gx);
        }
        for (int i = t; i < 1296; i += 256) {
            int ay = i / 36, ax = i - ay * 36;
            int gy = y0 - 2 + ay, gx = x0 - 2 + ax;
            float d = 0.0f;
            if (gy >= 0 && gy < GNY && gx >= 0 && gx < GNX)
                d = 1.0f / (1.0f + DT * sigma[gy * GNX + gx]);
            sDamp[ay * 37 + ax] = d;
        }
    }
    __syncthreads();

    // ---- phase A: predictor on 36x36 window, all LDS ----
    for (int i = t; i < 1296; i += 256) {
        int ay = i / 36, ax = i - ay * 36;
        int gy = y0 - 2 + ay, gx = x0 - 2 + ax;
        float un[3][3], vn[3][3], pn[3][3];
#pragma unroll
        for (int dy = 0; dy < 3; ++dy)
#pragma unroll
            for (int dx = 0; dx < 3; ++dx) {
                int li = (ay + dy) * 39 + ax + dx;
                un[dy][dx] = sU[li]; vn[dy][dx] = sV[li]; pn[dy][dx] = sP[li];
            }
        float buv, bvv;
        bool valid = !edge || (gy >= 0 && gy < GNY && gx >= 0 && gx < GNX);
        if (valid) {
            float dampv = sDamp[ay * 37 + ax];
            float gxp = conv_x3(pn) * DT, gyp = conv_y3(pn) * DT;
            float uc = un[1][1], vc = vn[1][1];
            buv = (uc + 0.5f * (NUc * conv_d3(un) * DT - uc * conv_x3(un) * DT - vc * conv_y3(un) * DT) - gxp) * dampv;
            bvv = (vc + 0.5f * (NUc * conv_d3(vn) * DT - uc * conv_x3(vn) * DT - vc * conv_y3(vn) * DT) - gyp) * dampv;
        } else if (gy < 0 || gy >= GNY || gx < 0) {
            buv = 1.0f; bvv = 0.0f;            // bc_u / bc_v ghost constants
        } else {
            buv = 0.0f; bvv = 0.0f;            // gx>=GNX: never read un-clamped
        }
        sBu[ay * 37 + ax] = buv;
        sBv[ay * 37 + ax] = bvv;
    }
    __syncthreads();

    // ---- phase B: corrector on 34x34 window ----
    float ucA[5], vcA[5];
    {
        int np = 0;
        for (int i = t; i < 1156; i += 256, ++np) {
            int cy = i / 34, cx = i - cy * 34;
            int li = (cy + 2) * 39 + cx + 2;
            ucA[np] = sU[li]; vcA[np] = sV[li];
        }
    }
    __syncthreads();
    {
        int np = 0;
        for (int i = t; i < 1156; i += 256, ++np) {
            int cy = i / 34, cx = i - cy * 34;
            int gy = y0 - 1 + cy, gx = x0 - 1 + cx;
            float u2_ = 0.0f, v2_ = 0.0f;
            bool valid = (gy >= 0 && gy < GNY && gx >= 0 && gx < GNX);
            if (valid) {
                float bun[3][3], bvn[3][3], pn[3][3];
                if (!rightcol) {
#pragma unroll
                    for (int dy = 0; dy < 3; ++dy)
#pragma unroll
                        for (int dx = 0; dx < 3; ++dx) {
                            int li = (cy + dy) * 37 + cx + dx;
                            bun[dy][dx] = sBu[li]; bvn[dy][dx] = sBv[li];
                            pn[dy][dx] = sP[(cy + dy + 1) * 39 + cx + dx + 1];
                        }
                } else {
#pragma unroll
                    for (int dy = 0; dy < 3; ++dy)
#pragma unroll
                        for (int dx = 0; dx < 3; ++dx) {
                            int yy = gy + dy - 1, xx = gx + dx - 1;
                            pn[dy][dx] = sP[(cy + dy + 1) * 39 + cx + dx + 1];
                            if (yy < 0 || yy >= GNY || xx < 0) { bun[dy][dx] = 1.0f; bvn[dy][dx] = 0.0f; }
                            else {
                                int cxx = (xx >= GNX) ? GNX - 1 : xx;
                                int li = (cy + dy) * 37 + (cxx - (x0 - 2));
                                bun[dy][dx] = sBu[li]; bvn[dy][dx] = sBv[li];
                            }
                        }
                }
                float gxp = conv_x3(pn) * DT, gyp = conv_y3(pn) * DT;
                float dampv = sDamp[(cy + 1) * 37 + cx + 1];
                float buc = bun[1][1], bvc = bvn[1][1];
                u2_ = (ucA[np] + NUc * conv_d3(bun) * DT - buc * conv_x3(bun) * DT - bvc * conv_y3(bun) * DT - gxp) * dampv;
                v2_ = (vcA[np] + NUc * conv_d3(bvn) * DT - buc * conv_x3(bvn) * DT - bvc * conv_y3(bvn) * DT - gyp) * dampv;
                if (cy >= 1 && cy <= 32 && cx >= 1 && cx <= 32) {
                    int idx = gy * GNX + gx;
                    u2g[idx] = u2_; v2g[idx] = v2_;
                }
            } else if (gy < 0 || gy >= GNY || gx < 0) {
                u2_ = 1.0f; v2_ = 0.0f;        // bc_u / bc_v ghost constants
            }
            sU2[cy * 35 + cx] = u2_;
            sV2[cy * 35 + cx] = v2_;
        }
    }
    __syncthreads();

    // ---- phase C: b on tile + r0 = A p - b ----
    for (int i = t; i < 1024; i += 256) {
        int ty = i >> 5, tx = i & 31;
        int gy = y0 + ty, gx = x0 + tx;
        float un[3][3], vn[3][3], pn[3][3];
        if (!rightcol) {
#pragma unroll
            for (int dy = 0; dy < 3; ++dy)
#pragma unroll
                for (int dx = 0; dx < 3; ++dx) {
                    int li = (ty + dy) * 35 + tx + dx;
                    un[dy][dx] = sU2[li]; vn[dy][dx] = sV2[li];
                    pn[dy][dx] = sP[(ty + dy + 2) * 39 + tx + dx + 2];
                }
        } else {
#pragma unroll
            for (int dy = 0; dy < 3; ++dy)
#pragma unroll
                for (int dx = 0; dx < 3; ++dx) {
                    int yy = gy + dy - 1, xx = gx + dx - 1;
                    pn[dy][dx] = sP[(ty + dy + 2) * 39 + tx + dx + 2];
                    if (yy < 0 || yy >= GNY || xx < 0) { un[dy][dx] = 1.0f; vn[dy][dx] = 0.0f; }
                    else {
                        int cxx = (xx >= GNX) ? GNX - 1 : xx;
                        int li = (ty + dy) * 35 + (cxx - (x0 - 1));
                        un[dy][dx] = sU2[li]; vn[dy][dx] = sV2[li];
                    }
                }
        }
        float b_ = -(conv_x3(un) + conv_y3(vn)) * (1.0f / DT);
        bg[gy * GNX + gx] = b_;
        s0[ty * 33 + tx] = conv_d3(pn) - b_;
    }
    __syncthreads();

    // ---- restriction chain r0 -> r1..r5 ----
    { int qy = t >> 4, qx = t & 15;
      float vv = 0.25f * (s0[(2*qy)*33 + 2*qx] + s0[(2*qy)*33 + 2*qx + 1]
                        + s0[(2*qy+1)*33 + 2*qx] + s0[(2*qy+1)*33 + 2*qx + 1]);
      s1[qy*17 + qx] = vv;
      r1[(by*16 + qy)*1024 + bx*16 + qx] = vv; }
    __syncthreads();
    if (t < 64) { int qy = t >> 3, qx = t & 7;
      float vv = 0.25f * (s1[(2*qy)*17 + 2*qx] + s1[(2*qy)*17 + 2*qx + 1]
                        + s1[(2*qy+1)*17 + 2*qx] + s1[(2*qy+1)*17 + 2*qx + 1]);
      s2[qy*9 + qx] = vv;
      r2[(by*8 + qy)*512 + bx*8 + qx] = vv; }
    __syncthreads();
    if (t < 16) { int qy = t >> 2, qx = t & 3;
      float vv = 0.25f * (s2[(2*qy)*9 + 2*qx] + s2[(2*qy)*9 + 2*qx + 1]
                        + s2[(2*qy+1)*9 + 2*qx] + s2[(2*qy+1)*9 + 2*qx + 1]);
      s3[qy*5 + qx] = vv;
      r3[(by*4 + qy)*256 + bx*4 + qx] = vv; }
    __syncthreads();
    if (t < 4) { int qy = t >> 1, qx = t & 1;
      float vv = 0.25f * (s3[(2*qy)*5 + 2*qx] + s3[(2*qy)*5 + 2*qx + 1]
                        + s3[(2*qy+1)*5 + 2*qx] + s3[(2*qy+1)*5 + 2*qx + 1]);
      s4[qy*3 + qx] = vv;
      r4[(by*2 + qy)*128 + bx*2 + qx] = vv; }
    __syncthreads();
    if (t == 0)
        r5[by*64 + bx] = 0.25f * (s4[0] + s4[1] + s4[3] + s4[4]);
}

// ---- ONE fused MG iteration; ALL global reads burst-staged at entry ----
__global__ __launch_bounds__(256) void k_mg(
        const float* __restrict__ p_src, const float* __restrict__ b,
        const float* __restrict__ r1, const float* __restrict__ r2,
        const float* __restrict__ r3, const float* __restrict__ r4,
        const float* __restrict__ r5,
        float* __restrict__ p_dst,
        float* __restrict__ o1, float* __restrict__ o2, float* __restrict__ o3,
        float* __restrict__ o4, float* __restrict__ o5,
        const float* __restrict__ sigma, float* __restrict__ u_io,
        float* __restrict__ v_io, int last) {
    __shared__ float L[6390];
    float* gR5 = L;            // 2048 (phase 1/2; then sPp overlays)
    float* gP  = L + 2048;     // 36x37=1332 (3a; then sPn overlays)
    float* gB  = L + 3380;     // 34x35=1190 (persists to end)
    float* gR1 = L + 4570;     // 324 (18x18 window)
    float* gR2 = L + 4894;     // 100 (10x10)
    float* gR3 = L + 4994;     // 36  (6x6)
    float* gR4 = L + 5030;     // 16  (4x4)
    float* s6  = L + 5046;     // 512
    float* s7  = L + 5558;     // 128
    float* s8  = L + 5686;     // 32
    float* s9  = L + 5718;     // 8
    float* s10 = L + 5726;     // 2
    float* a9  = L + 5728;     // 8
    float* a8  = L + 5736;     // 32
    float* a7  = L + 5768;     // 128
    float* w6v = L + 5896;     // 9
    float* w5v = L + 5905;     // 9
    float* w4v = L + 5914;     // 16
    float* w3v = L + 5930;     // 36
    float* w2v = L + 5966;     // 100
    float* w1v = L + 6066;     // 324 (ends 6390)
    // overlays:
    float* sPp = L;            // 36x37=1332 over gR5 (written in 3a, after phase 2)
    float* sPn = L + 2048;     // 34x35=1190 over gP (written in 3b, after 3a)
    float* s0  = L;            // 32x33=1056 over sPp (after 3b)
    float* s1  = L + 1056;     // 272
    float* s2  = L + 1328;     // 72
    float* s3  = L + 1400;     // 20
    float* s4  = L + 1420;     // 6

    int t = threadIdx.x;
    int bx = blockIdx.x, by = blockIdx.y;
    int y0 = by * 32, x0 = bx * 32;

    int w6ylo = (by - 2) >> 1, w6xlo = (bx - 2) >> 1;
    int w5ylo = by - 1,        w5xlo = bx - 1;
    int w4ylo = 2*by - 1,      w4xlo = 2*bx - 1;
    int w3ylo = 4*by - 1,      w3xlo = 4*bx - 1;
    int w2ylo = 8*by - 1,      w2xlo = 8*bx - 1;
    int w1ylo = 16*by - 1,     w1xlo = 16*bx - 1;

    // ---- burst staging: every global read of this WG, issued back-to-back ----
    for (int i = t; i < 2048; i += 256) gR5[i] = r5[i];
    for (int i = t; i < 1296; i += 256) {
        int wy = i / 36, wx = i - wy * 36;
        int yy = y0 - 2 + wy, xx = x0 - 2 + wx;
        float v = 0.0f;
        if (xx < GNX) {
            int cy = min(max(yy, 0), GNY - 1), cx = xx < 0 ? 0 : xx;
            v = p_src[cy * GNX + cx];
        }
        gP[wy * 37 + wx] = v;
    }
    for (int i = t; i < 1156; i += 256) {
        int wy = i / 34, wx = i - wy * 34;
        int yy = y0 - 1 + wy, xx = x0 - 1 + wx;
        float v = 0.0f;
        if (xx < GNX) {
            int cy = min(max(yy, 0), GNY - 1), cx = xx < 0 ? 0 : xx;
            v = b[cy * GNX + cx];
        }
        gB[wy * 35 + wx] = v;
    }
    for (int i = t; i < 324; i += 256) {
        int gy = w1ylo + i / 18, gx = w1xlo + i % 18;
        gR1[i] = (gy >= 0 && gy < 512 && gx >= 0 && gx < 1024) ? r1[gy * 1024 + gx] : 0.0f;
    }
    if (t < 100) { int gy = w2ylo + t / 10, gx = w2xlo + t % 10;
        gR2[t] = (gy >= 0 && gy < 256 && gx >= 0 && gx < 512) ? r2[gy * 512 + gx] : 0.0f; }
    if (t < 36)  { int gy = w3ylo + t / 6, gx = w3xlo + t % 6;
        gR3[t] = (gy >= 0 && gy < 128 && gx >= 0 && gx < 256) ? r3[gy * 256 + gx] : 0.0f; }
    if (t < 16)  { int gy = w4ylo + t / 4, gx = w4xlo + t % 4;
        gR4[t] = (gy >= 0 && gy < 64 && gx >= 0 && gx < 128) ? r4[gy * 128 + gx] : 0.0f; }
    __syncthreads();

    // ---- phase 1: full restriction r5 -> r10, full up a10->a7 (LDS-only) ----
    for (int i = t; i < 512; i += 256) {
        int y = i >> 5, x = i & 31;
        s6[i] = 0.25f * (gR5[(2*y)*64 + 2*x] + gR5[(2*y)*64 + 2*x + 1]
                       + gR5[(2*y+1)*64 + 2*x] + gR5[(2*y+1)*64 + 2*x + 1]);
    }
    __syncthreads();
    if (t < 128) { int y = t >> 4, x = t & 15;
        s7[t] = 0.25f * (s6[(2*y)*32 + 2*x] + s6[(2*y)*32 + 2*x + 1]
                       + s6[(2*y+1)*32 + 2*x] + s6[(2*y+1)*32 + 2*x + 1]); }
    __syncthreads();
    if (t < 32) { int y = t >> 3, x = t & 7;
        s8[t] = 0.25f * (s7[(2*y)*16 + 2*x] + s7[(2*y)*16 + 2*x + 1]
                       + s7[(2*y+1)*16 + 2*x] + s7[(2*y+1)*16 + 2*x + 1]); }
    __syncthreads();
    if (t < 8) { int y = t >> 2, x = t & 3;
        s9[t] = 0.25f * (s8[(2*y)*8 + 2*x] + s8[(2*y)*8 + 2*x + 1]
                       + s8[(2*y+1)*8 + 2*x] + s8[(2*y+1)*8 + 2*x + 1]); }
    __syncthreads();
    if (t < 2)
        s10[t] = 0.25f * (s9[2*t] + s9[2*t + 1] + s9[4 + 2*t] + s9[4 + 2*t + 1]);
    __syncthreads();
    if (t < 8) { int y = t >> 2, x = t & 3;
        a9[t] = up_val([&](int py, int px) { return s10[py*2 + px] * INV_DIAG; },
                       s9[t], 2, 4, y, x); }
    __syncthreads();
    if (t < 32) { int y = t >> 3, x = t & 7;
        a8[t] = up_val([&](int py, int px) { return a9[py*4 + px]; },
                       s8[t], 4, 8, y, x); }
    __syncthreads();
    if (t < 128) { int y = t >> 4, x = t & 15;
        a7[t] = up_val([&](int py, int px) { return a8[py*8 + px]; },
                       s7[t], 8, 16, y, x); }
    __syncthreads();

    // ---- phase 2: windowed up-sweep a6..a1 (LDS-only) ----
    if (t < 9) { int gy = w6ylo + t/3, gx = w6xlo + t%3;
        w6v[t] = (gy >= 0 && gy < 16 && gx >= 0 && gx < 32)
            ? up_val([&](int py, int px) { return a7[py*16 + px]; },
                     s6[gy*32 + gx], 16, 32, gy, gx) : 0.0f; }
    __syncthreads();
    if (t < 9) { int gy = w5ylo + t/3, gx = w5xlo + t%3;
        w5v[t] = (gy >= 0 && gy < 32 && gx >= 0 && gx < 64)
            ? up_val([&](int py, int px) { return w6v[(py - w6ylo)*3 + (px - w6xlo)]; },
                     gR5[gy*64 + gx], 32, 64, gy, gx) : 0.0f; }
    __syncthreads();
    if (t < 16) { int gy = w4ylo + t/4, gx = w4xlo + t%4;
        w4v[t] = (gy >= 0 && gy < 64 && gx >= 0 && gx < 128)
            ? up_val([&](int py, int px) { return w5v[(py - w5ylo)*3 + (px - w5xlo)]; },
                     gR4[t], 64, 128, gy, gx) : 0.0f; }
    __syncthreads();
    if (t < 36) { int gy = w3ylo + t/6, gx = w3xlo + t%6;
        w3v[t] = (gy >= 0 && gy < 128 && gx >= 0 && gx < 256)
            ? up_val([&](int py, int px) { return w4v[(py - w4ylo)*4 + (px - w4xlo)]; },
                     gR3[t], 128, 256, gy, gx) : 0.0f; }
    __syncthreads();
    if (t < 100) { int gy = w2ylo + t/10, gx = w2xlo + t%10;
        w2v[t] = (gy >= 0 && gy < 256 && gx >= 0 && gx < 512)
            ? up_val([&](int py, int px) { return w3v[(py - w3ylo)*6 + (px - w3xlo)]; },
                     gR2[t], 256, 512, gy, gx) : 0.0f; }
    __syncthreads();
    for (int i = t; i < 324; i += 256) { int gy = w1ylo + i/18, gx = w1xlo + i%18;
        w1v[i] = (gy >= 0 && gy < 512 && gx >= 0 && gx < 1024)
            ? up_val([&](int py, int px) { return w2v[(py - w2ylo)*10 + (px - w2xlo)]; },
                     gR1[i], 512, 1024, gy, gx) : 0.0f; }
    __syncthreads();

    // ---- phase 3a: sPp = bc_p-mapped p' = p - P(a1) on 36x36 (overlays gR5) ----
    for (int i = t; i < 1296; i += 256) {
        int wy = i / 36, wx = i - wy * 36;
        int yy = y0 - 2 + wy, xx = x0 - 2 + wx;
        float v = 0.0f;
        if (xx < GNX) {
            int cy = min(max(yy, 0), GNY - 1), cx = xx < 0 ? 0 : xx;
            v = gP[wy*37 + wx] - w1v[((cy >> 1) - w1ylo)*18 + ((cx >> 1) - w1xlo)];
        }
        sPp[wy*37 + wx] = v;
    }
    __syncthreads();
    // ---- phase 3b: sPn = bc_p-mapped p_next on 34x34 (overlays gP) ----
    for (int i = t; i < 1156; i += 256) {
        int wy = i / 34, wx = i - wy * 34;
        int xx = x0 - 1 + wx;
        float v = 0.0f;
        if (xx < GNX) {
            float m[3][3];
#pragma unroll
            for (int dy = 0; dy < 3; ++dy)
#pragma unroll
                for (int dx = 0; dx < 3; ++dx)
                    m[dy][dx] = sPp[(wy + dy)*37 + (wx + dx)];
            float conv = (m[0][0] + m[0][1] + m[0][2] + m[1][0] + m[1][2]
                          + m[2][0] + m[2][1] + m[2][2] - 8.0f*m[1][1]) * (1.0f / 3.0f);
            v = m[1][1] - conv * INV_DIAG + gB[wy*35 + wx] * INV_DIAG;
        }
        sPn[wy*35 + wx] = v;
    }
    __syncthreads();
    // write own p tile
    for (int i = t; i < 1024; i += 256) {
        int ty = i >> 5, tx = i & 31;
        p_dst[(y0 + ty)*GNX + x0 + tx] = sPn[(ty + 1)*35 + (tx + 1)];
    }

    if (!last) {
        // next-iteration residual on tile + restriction (reads sPn/gB only)
        for (int i = t; i < 1024; i += 256) {
            int ty = i >> 5, tx = i & 31;
            float m[3][3];
#pragma unroll
            for (int dy = 0; dy < 3; ++dy)
#pragma unroll
                for (int dx = 0; dx < 3; ++dx)
                    m[dy][dx] = sPn[(ty + dy)*35 + (tx + dx)];
            s0[ty*33 + tx] = conv_d3(m) - gB[(ty + 1)*35 + (tx + 1)];
        }
        __syncthreads();
        { int qy = t >> 4, qx = t & 15;
          float v = 0.25f * (s0[(2*qy)*33 + 2*qx] + s0[(2*qy)*33 + 2*qx + 1]
                           + s0[(2*qy+1)*33 + 2*qx] + s0[(2*qy+1)*33 + 2*qx + 1]);
          s1[qy*17 + qx] = v;
          o1[(by*16 + qy)*1024 + bx*16 + qx] = v; }
        __syncthreads();
        if (t < 64) { int qy = t >> 3, qx = t & 7;
          float v = 0.25f * (s1[(2*qy)*17 + 2*qx] + s1[(2*qy)*17 + 2*qx + 1]
                           + s1[(2*qy+1)*17 + 2*qx] + s1[(2*qy+1)*17 + 2*qx + 1]);
          s2[qy*9 + qx] = v;
          o2[(by*8 + qy)*512 + bx*8 + qx] = v; }
        __syncthreads();
        if (t < 16) { int qy = t >> 2, qx = t & 3;
          float v = 0.25f * (s2[(2*qy)*9 + 2*qx] + s2[(2*qy)*9 + 2*qx + 1]
                           + s2[(2*qy+1)*9 + 2*qx] + s2[(2*qy+1)*9 + 2*qx + 1]);
          s3[qy*5 + qx] = v;
          o3[(by*4 + qy)*256 + bx*4 + qx] = v; }
        __syncthreads();
        if (t < 4) { int qy = t >> 1, qx = t & 1;
          float v = 0.25f * (s3[(2*qy)*5 + 2*qx] + s3[(2*qy)*5 + 2*qx + 1]
                           + s3[(2*qy+1)*5 + 2*qx] + s3[(2*qy+1)*5 + 2*qx + 1]);
          s4[qy*3 + qx] = v;
          o4[(by*2 + qy)*128 + bx*2 + qx] = v; }
        __syncthreads();
        if (t == 0)
            o5[by*64 + bx] = 0.25f * (s4[0] + s4[1] + s4[3] + s4[4]);
    } else {
        // fused projection
        for (int i = t; i < 1024; i += 256) {
            int ty = i >> 5, tx = i & 31;
            float m[3][3];
#pragma unroll
            for (int dy = 0; dy < 3; ++dy)
#pragma unroll
                for (int dx = 0; dx < 3; ++dx)
                    m[dy][dx] = sPn[(ty + dy)*35 + (tx + dx)];
            int idx = (y0 + ty)*GNX + x0 + tx;
            float damp = 1.0f / (1.0f + DT * sigma[idx]);
            u_io[idx] = (u_io[idx] - conv_x3(m) * DT) * damp;
            v_io[idx] = (v_io[idx] - conv_y3(m) * DT) * damp;
        }
    }
}

extern "C" void kernel_launch(void* const* d_in, const int* in_sizes, int n_in,
                              void* d_out, int out_size, void* d_ws, size_t ws_size,
                              hipStream_t stream) {
    (void)in_sizes; (void)n_in; (void)out_size; (void)ws_size;
    const float* u_in  = (const float*)d_in[0];
    const float* v_in  = (const float*)d_in[1];
    const float* p_in  = (const float*)d_in[2];
    const float* sigma = (const float*)d_in[3];

    float* out_u = (float*)d_out;
    float* out_v = out_u + GNPTS;
    float* out_p = out_u + 2 * (size_t)GNPTS;

    float* ws   = (float*)d_ws;
    float* b    = ws;
    float* p_ws = b + (size_t)GNPTS;
    float* base = p_ws + (size_t)GNPTS;
    float* A_[5], * B_[5];
    size_t lsz[5] = {524288, 131072, 32768, 8192, 2048};
    float* cur = base;
    for (int l = 0; l < 5; ++l) { A_[l] = cur; cur += lsz[l]; }
    for (int l = 0; l < 5; ++l) { B_[l] = cur; cur += lsz[l]; }

    dim3 grdT(GNX / 32, GNY / 32), blkT(256);

    k_front<<<grdT, blkT, 0, stream>>>(u_in, v_in, p_in, sigma,
                                       out_u, out_v, b,
                                       A_[0], A_[1], A_[2], A_[3], A_[4]);

    const float* p_cur = p_in;
    float* p_bufs[2] = { out_p, p_ws };   // it0->out_p, it1->p_ws, ..., it4->out_p
    for (int it = 0; it < 5; ++it) {
        float** rp = (it % 2 == 0) ? A_ : B_;
        float** wp = (it % 2 == 0) ? B_ : A_;
        float* p_next = p_bufs[it % 2];
        int last = (it == 4) ? 1 : 0;
        k_mg<<<grdT, blkT, 0, stream>>>(p_cur, b,
                                        rp[0], rp[1], rp[2], rp[3], rp[4],
                                        p_next,
                                        wp[0], wp[1], wp[2], wp[3], wp[4],
                                        sigma, out_u, out_v, last);
        p_cur = p_next;
    }
}

// Round 7
// 217.172 us; speedup vs baseline: 1.3429x; 1.3429x over previous
//
#include <hip/hip_runtime.h>
#include <cstdint>

#define GNY 1024
#define GNX 2048
#define GNPTS (GNY * GNX)

namespace {
constexpr float DT = 0.1f;
constexpr float NUc = 0.01f;
constexpr float INV_DIAG = -0.375f;   // 1/DIAG, DIAG = -8/(3*dx^2) = -8/3
}

// ---- boundary-condition index maps (verified against JAX .at[].set order) ----
__device__ __forceinline__ float bc_u_at(const float* __restrict__ f, int y, int x) {
    if (y < 0 || y >= GNY || x < 0) return 1.0f;
    if (x >= GNX) x = GNX - 1;
    return f[y * GNX + x];
}
__device__ __forceinline__ float bc_v_at(const float* __restrict__ f, int y, int x) {
    if (y < 0 || y >= GNY || x < 0) return 0.0f;
    if (x >= GNX) x = GNX - 1;
    return f[y * GNX + x];
}
__device__ __forceinline__ float bc_p_at(const float* __restrict__ f, int y, int x) {
    if (x >= GNX) return 0.0f;          // right ghost = 0 (dominates corners)
    if (x < 0) x = 0;
    y = min(max(y, 0), GNY - 1);
    return f[y * GNX + x];
}

// ---- stencils (cross-correlation, m[dy][dx] = f(y+dy-1, x+dx-1)) ----
__device__ __forceinline__ float conv_x3(const float m[3][3]) {
    return ((m[0][2] - m[0][0]) + 4.0f * (m[1][2] - m[1][0]) + (m[2][2] - m[2][0])) * (1.0f / 12.0f);
}
__device__ __forceinline__ float conv_y3(const float m[3][3]) {
    return ((m[2][0] - m[0][0]) + 4.0f * (m[2][1] - m[0][1]) + (m[2][2] - m[0][2])) * (1.0f / 12.0f);
}
__device__ __forceinline__ float conv_d3(const float m[3][3]) {
    return (m[0][0] + m[0][1] + m[0][2] + m[1][0] + m[1][2] + m[2][0] + m[2][1] + m[2][2]
            - 8.0f * m[1][1]) * (1.0f / 3.0f);
}

// up-step value: a(y,x) = P(par)(y,x) - conv(bc0(P(par)))/DIAG + r/DIAG at level (H,W)
template <typename PG>
__device__ __forceinline__ float up_val(PG pget, float rval, int H, int W, int y, int x) {
    float m[3][3];
#pragma unroll
    for (int dy = 0; dy < 3; ++dy)
#pragma unroll
        for (int dx = 0; dx < 3; ++dx) {
            int yy = y + dy - 1, xx = x + dx - 1;
            m[dy][dx] = (yy >= 0 && yy < H && xx >= 0 && xx < W) ? pget(yy >> 1, xx >> 1) : 0.0f;
        }
    float conv = (m[0][0] + m[0][1] + m[0][2] + m[1][0] + m[1][2]
                  + m[2][0] + m[2][1] + m[2][2] - 8.0f * m[1][1]) * (1.0f / 3.0f);
    return m[1][1] - conv * INV_DIAG + rval * INV_DIAG;
}

// ---- FUSED front-end with bc-mapped LDS staging ----
// LDS trimmed to 28.4 KB (no sDamp) -> 5 blocks/CU instead of 4.
__global__ __launch_bounds__(256) void k_front(
        const float* __restrict__ u, const float* __restrict__ v,
        const float* __restrict__ p, const float* __restrict__ sigma,
        float* __restrict__ u2g, float* __restrict__ v2g, float* __restrict__ bg,
        float* __restrict__ r1, float* __restrict__ r2, float* __restrict__ r3,
        float* __restrict__ r4, float* __restrict__ r5) {
    __shared__ float scrF[7110];
    float* sP    = scrF;              // 38x38 stride 39 (1482), origin (y0-3,x0-3), persists
    float* sU    = scrF + 1482;       // phase A (1482)
    float* sV    = scrF + 2964;       // phase A (1482)
    float* sU2   = scrF + 1482;       // phase B overlay, 34x35 (1190), origin (y0-1,x0-1)
    float* sV2   = scrF + 2672;       // (1190)
    float* sBu   = scrF + 4446;       // 36x37 (1332), origin (y0-2,x0-2)
    float* sBv   = scrF + 5778;       // (1332, ends 7110)
    float* s0    = scrF + 4446;       // phase C overlay: 32x33 (1056)
    float* s1    = scrF + 5502;       // 16x17 (272)
    float* s2    = scrF + 5774;       // 8x9 (72)
    float* s3    = scrF + 5846;       // 4x5 (20)
    float* s4    = scrF + 5866;       // 2x3 (6)

    int t = threadIdx.x;
    int bx = blockIdx.x, by = blockIdx.y;
    int y0 = by * 32, x0 = bx * 32;
    bool edge = !(bx >= 1 && bx <= 62 && by >= 1 && by <= 30);
    bool rightcol = (bx == 63);

    // ---- staging: bc-mapped u/v/p on 38x38 ----
    if (!edge) {
        for (int i = t; i < 1444; i += 256) {
            int wy = i / 38, wx = i - wy * 38;
            int idx = (y0 - 3 + wy) * GNX + (x0 - 3 + wx);
            sP[wy * 39 + wx] = p[idx];
            sU[wy * 39 + wx] = u[idx];
            sV[wy * 39 + wx] = v[idx];
        }
    } else {
        for (int i = t; i < 1444; i += 256) {
            int wy = i / 38, wx = i - wy * 38;
            int gy = y0 - 3 + wy, gx = x0 - 3 + wx;
            sP[wy * 39 + wx] = bc_p_at(p, gy, gx);
            sU[wy * 39 + wx] = bc_u_at(u, gy, gx);
            sV[wy * 39 + wx] = bc_v_at(v, gy, gx);
        }
    }
    __syncthreads();

    // ---- phase A: predictor on 36x36 window, taps unconditional ----
    for (int i = t; i < 1296; i += 256) {
        int ay = i / 36, ax = i - ay * 36;
        int gy = y0 - 2 + ay, gx = x0 - 2 + ax;
        float un[3][3], vn[3][3], pn[3][3];
#pragma unroll
        for (int dy = 0; dy < 3; ++dy)
#pragma unroll
            for (int dx = 0; dx < 3; ++dx) {
                int li = (ay + dy) * 39 + ax + dx;
                un[dy][dx] = sU[li]; vn[dy][dx] = sV[li]; pn[dy][dx] = sP[li];
            }
        float buv, bvv;
        bool valid = !edge || (gy >= 0 && gy < GNY && gx >= 0 && gx < GNX);
        if (valid) {
            float dampv = 1.0f / (1.0f + DT * sigma[gy * GNX + gx]);
            float gxp = conv_x3(pn) * DT, gyp = conv_y3(pn) * DT;
            float uc = un[1][1], vc = vn[1][1];
            buv = (uc + 0.5f * (NUc * conv_d3(un) * DT - uc * conv_x3(un) * DT - vc * conv_y3(un) * DT) - gxp) * dampv;
            bvv = (vc + 0.5f * (NUc * conv_d3(vn) * DT - uc * conv_x3(vn) * DT - vc * conv_y3(vn) * DT) - gyp) * dampv;
        } else if (gy < 0 || gy >= GNY || gx < 0) {
            buv = 1.0f; bvv = 0.0f;            // bc_u / bc_v ghost constants
        } else {
            buv = 0.0f; bvv = 0.0f;            // gx>=GNX: never read un-clamped
        }
        sBu[ay * 37 + ax] = buv;
        sBv[ay * 37 + ax] = bvv;
    }
    __syncthreads();

    // ---- phase B: corrector on 34x34 window ----
    float ucA[5], vcA[5];
    {
        int np = 0;
        for (int i = t; i < 1156; i += 256, ++np) {
            int cy = i / 34, cx = i - cy * 34;
            int li = (cy + 2) * 39 + cx + 2;
            ucA[np] = sU[li]; vcA[np] = sV[li];
        }
    }
    __syncthreads();
    {
        int np = 0;
        for (int i = t; i < 1156; i += 256, ++np) {
            int cy = i / 34, cx = i - cy * 34;
            int gy = y0 - 1 + cy, gx = x0 - 1 + cx;
            float u2_ = 0.0f, v2_ = 0.0f;
            bool valid = (gy >= 0 && gy < GNY && gx >= 0 && gx < GNX);
            if (valid) {
                float bun[3][3], bvn[3][3], pn[3][3];
                if (!rightcol) {
#pragma unroll
                    for (int dy = 0; dy < 3; ++dy)
#pragma unroll
                        for (int dx = 0; dx < 3; ++dx) {
                            int li = (cy + dy) * 37 + cx + dx;
                            bun[dy][dx] = sBu[li]; bvn[dy][dx] = sBv[li];
                            pn[dy][dx] = sP[(cy + dy + 1) * 39 + cx + dx + 1];
                        }
                } else {
#pragma unroll
                    for (int dy = 0; dy < 3; ++dy)
#pragma unroll
                        for (int dx = 0; dx < 3; ++dx) {
                            int yy = gy + dy - 1, xx = gx + dx - 1;
                            pn[dy][dx] = sP[(cy + dy + 1) * 39 + cx + dx + 1];
                            if (yy < 0 || yy >= GNY || xx < 0) { bun[dy][dx] = 1.0f; bvn[dy][dx] = 0.0f; }
                            else {
                                int cxx = (xx >= GNX) ? GNX - 1 : xx;
                                int li = (cy + dy) * 37 + (cxx - (x0 - 2));
                                bun[dy][dx] = sBu[li]; bvn[dy][dx] = sBv[li];
                            }
                        }
                }
                int idx = gy * GNX + gx;
                float gxp = conv_x3(pn) * DT, gyp = conv_y3(pn) * DT;
                float dampv = 1.0f / (1.0f + DT * sigma[idx]);
                float buc = bun[1][1], bvc = bvn[1][1];
                u2_ = (ucA[np] + NUc * conv_d3(bun) * DT - buc * conv_x3(bun) * DT - bvc * conv_y3(bun) * DT - gxp) * dampv;
                v2_ = (vcA[np] + NUc * conv_d3(bvn) * DT - buc * conv_x3(bvn) * DT - bvc * conv_y3(bvn) * DT - gyp) * dampv;
                if (cy >= 1 && cy <= 32 && cx >= 1 && cx <= 32) {
                    u2g[idx] = u2_; v2g[idx] = v2_;
                }
            } else if (gy < 0 || gy >= GNY || gx < 0) {
                u2_ = 1.0f; v2_ = 0.0f;        // bc_u / bc_v ghost constants
            }
            sU2[cy * 35 + cx] = u2_;
            sV2[cy * 35 + cx] = v2_;
        }
    }
    __syncthreads();

    // ---- phase C: b on tile + r0 = A p - b ----
    for (int i = t; i < 1024; i += 256) {
        int ty = i >> 5, tx = i & 31;
        int gy = y0 + ty, gx = x0 + tx;
        float un[3][3], vn[3][3], pn[3][3];
        if (!rightcol) {
#pragma unroll
            for (int dy = 0; dy < 3; ++dy)
#pragma unroll
                for (int dx = 0; dx < 3; ++dx) {
                    int li = (ty + dy) * 35 + tx + dx;
                    un[dy][dx] = sU2[li]; vn[dy][dx] = sV2[li];
                    pn[dy][dx] = sP[(ty + dy + 2) * 39 + tx + dx + 2];
                }
        } else {
#pragma unroll
            for (int dy = 0; dy < 3; ++dy)
#pragma unroll
                for (int dx = 0; dx < 3; ++dx) {
                    int yy = gy + dy - 1, xx = gx + dx - 1;
                    pn[dy][dx] = sP[(ty + dy + 2) * 39 + tx + dx + 2];
                    if (yy < 0 || yy >= GNY || xx < 0) { un[dy][dx] = 1.0f; vn[dy][dx] = 0.0f; }
                    else {
                        int cxx = (xx >= GNX) ? GNX - 1 : xx;
                        int li = (ty + dy) * 35 + (cxx - (x0 - 1));
                        un[dy][dx] = sU2[li]; vn[dy][dx] = sV2[li];
                    }
                }
        }
        float b_ = -(conv_x3(un) + conv_y3(vn)) * (1.0f / DT);
        bg[gy * GNX + gx] = b_;
        s0[ty * 33 + tx] = conv_d3(pn) - b_;
    }
    __syncthreads();

    // ---- restriction chain r0 -> r1..r5 ----
    { int qy = t >> 4, qx = t & 15;
      float vv = 0.25f * (s0[(2*qy)*33 + 2*qx] + s0[(2*qy)*33 + 2*qx + 1]
                        + s0[(2*qy+1)*33 + 2*qx] + s0[(2*qy+1)*33 + 2*qx + 1]);
      s1[qy*17 + qx] = vv;
      r1[(by*16 + qy)*1024 + bx*16 + qx] = vv; }
    __syncthreads();
    if (t < 64) { int qy = t >> 3, qx = t & 7;
      float vv = 0.25f * (s1[(2*qy)*17 + 2*qx] + s1[(2*qy)*17 + 2*qx + 1]
                        + s1[(2*qy+1)*17 + 2*qx] + s1[(2*qy+1)*17 + 2*qx + 1]);
      s2[qy*9 + qx] = vv;
      r2[(by*8 + qy)*512 + bx*8 + qx] = vv; }
    __syncthreads();
    if (t < 16) { int qy = t >> 2, qx = t & 3;
      float vv = 0.25f * (s2[(2*qy)*9 + 2*qx] + s2[(2*qy)*9 + 2*qx + 1]
                        + s2[(2*qy+1)*9 + 2*qx] + s2[(2*qy+1)*9 + 2*qx + 1]);
      s3[qy*5 + qx] = vv;
      r3[(by*4 + qy)*256 + bx*4 + qx] = vv; }
    __syncthreads();
    if (t < 4) { int qy = t >> 1, qx = t & 1;
      float vv = 0.25f * (s3[(2*qy)*5 + 2*qx] + s3[(2*qy)*5 + 2*qx + 1]
                        + s3[(2*qy+1)*5 + 2*qx] + s3[(2*qy+1)*5 + 2*qx + 1]);
      s4[qy*3 + qx] = vv;
      r4[(by*2 + qy)*128 + bx*2 + qx] = vv; }
    __syncthreads();
    if (t == 0)
        r5[by*64 + bx] = 0.25f * (s4[0] + s4[1] + s4[3] + s4[4]);
}

// ---- ONE fused MG iteration (verified round-5 version, reverted) ----
__global__ __launch_bounds__(256) void k_mg(
        const float* __restrict__ p_src, const float* __restrict__ b,
        const float* __restrict__ r1, const float* __restrict__ r2,
        const float* __restrict__ r3, const float* __restrict__ r4,
        const float* __restrict__ r5,
        float* __restrict__ p_dst,
        float* __restrict__ o1, float* __restrict__ o2, float* __restrict__ o3,
        float* __restrict__ o4, float* __restrict__ o5,
        const float* __restrict__ sigma, float* __restrict__ u_io,
        float* __restrict__ v_io, int last) {
    __shared__ float scr[3948];
    __shared__ float w6v[9], w5v[9], w4v[16], w3v[36], w2v[100], w1v[324];
    float* s5  = scr;            // 32x64 = 2048
    float* s6  = scr + 2048;     // 16x32 = 512
    float* s7  = scr + 2560;     // 8x16  = 128
    float* s8  = scr + 2688;     // 4x8   = 32
    float* s9  = scr + 2720;     // 2x4   = 8
    float* s10 = scr + 2728;     // 1x2   = 2
    float* a9  = scr + 2730;     // 8
    float* a8  = scr + 2738;     // 32
    float* a7  = scr + 2770;     // 128
    float* sPp = scr;            // 36x36, stride 37 = 1332 (bc_p-mapped p')
    float* sPn = scr + 1332;     // 34x34, stride 35 = 1190 (bc_p-mapped p_next)
    float* s0  = scr + 2522;     // 32x33 = 1056
    float* s1  = scr + 3578;     // 16x17 = 272
    float* s2  = scr + 3850;     // 8x9   = 72
    float* s3  = scr + 3922;     // 4x5   = 20
    float* s4  = scr + 3942;     // 2x3   = 6

    int t = threadIdx.x;
    int bx = blockIdx.x, by = blockIdx.y;
    int y0 = by * 32, x0 = bx * 32;

    // phase 1: full restriction r5 -> r10, tiny full up levels a10->a7
    for (int i = t; i < 2048; i += 256) s5[i] = r5[i];
    __syncthreads();
    for (int i = t; i < 512; i += 256) {
        int y = i >> 5, x = i & 31;
        s6[i] = 0.25f * (s5[(2*y)*64 + 2*x] + s5[(2*y)*64 + 2*x + 1]
                       + s5[(2*y+1)*64 + 2*x] + s5[(2*y+1)*64 + 2*x + 1]);
    }
    __syncthreads();
    if (t < 128) { int y = t >> 4, x = t & 15;
        s7[t] = 0.25f * (s6[(2*y)*32 + 2*x] + s6[(2*y)*32 + 2*x + 1]
                       + s6[(2*y+1)*32 + 2*x] + s6[(2*y+1)*32 + 2*x + 1]); }
    __syncthreads();
    if (t < 32) { int y = t >> 3, x = t & 7;
        s8[t] = 0.25f * (s7[(2*y)*16 + 2*x] + s7[(2*y)*16 + 2*x + 1]
                       + s7[(2*y+1)*16 + 2*x] + s7[(2*y+1)*16 + 2*x + 1]); }
    __syncthreads();
    if (t < 8) { int y = t >> 2, x = t & 3;
        s9[t] = 0.25f * (s8[(2*y)*8 + 2*x] + s8[(2*y)*8 + 2*x + 1]
                       + s8[(2*y+1)*8 + 2*x] + s8[(2*y+1)*8 + 2*x + 1]); }
    __syncthreads();
    if (t < 2)
        s10[t] = 0.25f * (s9[2*t] + s9[2*t + 1] + s9[4 + 2*t] + s9[4 + 2*t + 1]);
    __syncthreads();
    if (t < 8) { int y = t >> 2, x = t & 3;
        a9[t] = up_val([&](int py, int px) { return s10[py*2 + px] * INV_DIAG; },
                       s9[t], 2, 4, y, x); }
    __syncthreads();
    if (t < 32) { int y = t >> 3, x = t & 7;
        a8[t] = up_val([&](int py, int px) { return a9[py*4 + px]; },
                       s8[t], 4, 8, y, x); }
    __syncthreads();
    if (t < 128) { int y = t >> 4, x = t & 15;
        a7[t] = up_val([&](int py, int px) { return a8[py*8 + px]; },
                       s7[t], 8, 16, y, x); }
    __syncthreads();

    // phase 2: windowed up-sweep a6..a1
    int w6ylo = (by - 2) >> 1, w6xlo = (bx - 2) >> 1;
    int w5ylo = by - 1,        w5xlo = bx - 1;
    int w4ylo = 2*by - 1,      w4xlo = 2*bx - 1;
    int w3ylo = 4*by - 1,      w3xlo = 4*bx - 1;
    int w2ylo = 8*by - 1,      w2xlo = 8*bx - 1;
    int w1ylo = 16*by - 1,     w1xlo = 16*bx - 1;

    if (t < 9) { int gy = w6ylo + t/3, gx = w6xlo + t%3;
        w6v[t] = (gy >= 0 && gy < 16 && gx >= 0 && gx < 32)
            ? up_val([&](int py, int px) { return a7[py*16 + px]; },
                     s6[gy*32 + gx], 16, 32, gy, gx) : 0.0f; }
    __syncthreads();
    if (t < 9) { int gy = w5ylo + t/3, gx = w5xlo + t%3;
        w5v[t] = (gy >= 0 && gy < 32 && gx >= 0 && gx < 64)
            ? up_val([&](int py, int px) { return w6v[(py - w6ylo)*3 + (px - w6xlo)]; },
                     s5[gy*64 + gx], 32, 64, gy, gx) : 0.0f; }
    __syncthreads();
    if (t < 16) { int gy = w4ylo + t/4, gx = w4xlo + t%4;
        w4v[t] = (gy >= 0 && gy < 64 && gx >= 0 && gx < 128)
            ? up_val([&](int py, int px) { return w5v[(py - w5ylo)*3 + (px - w5xlo)]; },
                     r4[gy*128 + gx], 64, 128, gy, gx) : 0.0f; }
    __syncthreads();
    if (t < 36) { int gy = w3ylo + t/6, gx = w3xlo + t%6;
        w3v[t] = (gy >= 0 && gy < 128 && gx >= 0 && gx < 256)
            ? up_val([&](int py, int px) { return w4v[(py - w4ylo)*4 + (px - w4xlo)]; },
                     r3[gy*256 + gx], 128, 256, gy, gx) : 0.0f; }
    __syncthreads();
    if (t < 100) { int gy = w2ylo + t/10, gx = w2xlo + t%10;
        w2v[t] = (gy >= 0 && gy < 256 && gx >= 0 && gx < 512)
            ? up_val([&](int py, int px) { return w3v[(py - w3ylo)*6 + (px - w3xlo)]; },
                     r2[gy*512 + gx], 256, 512, gy, gx) : 0.0f; }
    __syncthreads();
    for (int i = t; i < 324; i += 256) { int gy = w1ylo + i/18, gx = w1xlo + i%18;
        w1v[i] = (gy >= 0 && gy < 512 && gx >= 0 && gx < 1024)
            ? up_val([&](int py, int px) { return w2v[(py - w2ylo)*10 + (px - w2xlo)]; },
                     r1[gy*1024 + gx], 512, 1024, gy, gx) : 0.0f; }
    __syncthreads();

    // phase 3a: sPp = bc_p-mapped p' on 36x36 window
    for (int i = t; i < 1296; i += 256) {
        int wy = i / 36, wx = i - wy * 36;
        int yy = y0 - 2 + wy, xx = x0 - 2 + wx;
        float v = 0.0f;
        if (xx < GNX) {
            int cy = min(max(yy, 0), GNY - 1);
            int cx = xx < 0 ? 0 : xx;
            v = p_src[cy*GNX + cx] - w1v[((cy >> 1) - w1ylo)*18 + ((cx >> 1) - w1xlo)];
        }
        sPp[wy*37 + wx] = v;
    }
    __syncthreads();
    // phase 3b: sPn = bc_p-mapped p_next on 34x34 window (clamp-then-stencil!)
    for (int i = t; i < 1156; i += 256) {
        int wy = i / 34, wx = i - wy * 34;
        int yy = y0 - 1 + wy, xx = x0 - 1 + wx;
        float v = 0.0f;
        if (xx < GNX) {
            int cy = min(max(yy, 0), GNY - 1);
            int cx = xx < 0 ? 0 : xx;
            int rb = cy - y0 + 2, cb = cx - x0 + 2;   // sPp coords of clamped center
            float m[3][3];
#pragma unroll
            for (int dy = 0; dy < 3; ++dy)
#pragma unroll
                for (int dx = 0; dx < 3; ++dx)
                    m[dy][dx] = sPp[(rb + dy - 1)*37 + (cb + dx - 1)];
            float conv = (m[0][0] + m[0][1] + m[0][2] + m[1][0] + m[1][2]
                          + m[2][0] + m[2][1] + m[2][2] - 8.0f*m[1][1]) * (1.0f / 3.0f);
            v = m[1][1] - conv * INV_DIAG + b[cy*GNX + cx] * INV_DIAG;
        }
        sPn[wy*35 + wx] = v;
    }
    __syncthreads();
    // write own p tile
    for (int i = t; i < 1024; i += 256) {
        int ty = i >> 5, tx = i & 31;
        p_dst[(y0 + ty)*GNX + x0 + tx] = sPn[(ty + 1)*35 + (tx + 1)];
    }

    if (!last) {
        // next-iteration residual on tile (taps unconditional) + restriction
        for (int i = t; i < 1024; i += 256) {
            int ty = i >> 5, tx = i & 31;
            float m[3][3];
#pragma unroll
            for (int dy = 0; dy < 3; ++dy)
#pragma unroll
                for (int dx = 0; dx < 3; ++dx)
                    m[dy][dx] = sPn[(ty + dy)*35 + (tx + dx)];
            s0[ty*33 + tx] = conv_d3(m) - b[(y0 + ty)*GNX + x0 + tx];
        }
        __syncthreads();
        { int qy = t >> 4, qx = t & 15;
          float v = 0.25f * (s0[(2*qy)*33 + 2*qx] + s0[(2*qy)*33 + 2*qx + 1]
                           + s0[(2*qy+1)*33 + 2*qx] + s0[(2*qy+1)*33 + 2*qx + 1]);
          s1[qy*17 + qx] = v;
          o1[(by*16 + qy)*1024 + bx*16 + qx] = v; }
        __syncthreads();
        if (t < 64) { int qy = t >> 3, qx = t & 7;
          float v = 0.25f * (s1[(2*qy)*17 + 2*qx] + s1[(2*qy)*17 + 2*qx + 1]
                           + s1[(2*qy+1)*17 + 2*qx] + s1[(2*qy+1)*17 + 2*qx + 1]);
          s2[qy*9 + qx] = v;
          o2[(by*8 + qy)*512 + bx*8 + qx] = v; }
        __syncthreads();
        if (t < 16) { int qy = t >> 2, qx = t & 3;
          float v = 0.25f * (s2[(2*qy)*9 + 2*qx] + s2[(2*qy)*9 + 2*qx + 1]
                           + s2[(2*qy+1)*9 + 2*qx] + s2[(2*qy+1)*9 + 2*qx + 1]);
          s3[qy*5 + qx] = v;
          o3[(by*4 + qy)*256 + bx*4 + qx] = v; }
        __syncthreads();
        if (t < 4) { int qy = t >> 1, qx = t & 1;
          float v = 0.25f * (s3[(2*qy)*5 + 2*qx] + s3[(2*qy)*5 + 2*qx + 1]
                           + s3[(2*qy+1)*5 + 2*qx] + s3[(2*qy+1)*5 + 2*qx + 1]);
          s4[qy*3 + qx] = v;
          o4[(by*2 + qy)*128 + bx*2 + qx] = v; }
        __syncthreads();
        if (t == 0)
            o5[by*64 + bx] = 0.25f * (s4[0] + s4[1] + s4[3] + s4[4]);
    } else {
        // fused projection (taps unconditional)
        for (int i = t; i < 1024; i += 256) {
            int ty = i >> 5, tx = i & 31;
            float m[3][3];
#pragma unroll
            for (int dy = 0; dy < 3; ++dy)
#pragma unroll
                for (int dx = 0; dx < 3; ++dx)
                    m[dy][dx] = sPn[(ty + dy)*35 + (tx + dx)];
            int idx = (y0 + ty)*GNX + x0 + tx;
            float damp = 1.0f / (1.0f + DT * sigma[idx]);
            u_io[idx] = (u_io[idx] - conv_x3(m) * DT) * damp;
            v_io[idx] = (v_io[idx] - conv_y3(m) * DT) * damp;
        }
    }
}

extern "C" void kernel_launch(void* const* d_in, const int* in_sizes, int n_in,
                              void* d_out, int out_size, void* d_ws, size_t ws_size,
                              hipStream_t stream) {
    (void)in_sizes; (void)n_in; (void)out_size; (void)ws_size;
    const float* u_in  = (const float*)d_in[0];
    const float* v_in  = (const float*)d_in[1];
    const float* p_in  = (const float*)d_in[2];
    const float* sigma = (const float*)d_in[3];

    float* out_u = (float*)d_out;
    float* out_v = out_u + GNPTS;
    float* out_p = out_u + 2 * (size_t)GNPTS;

    float* ws   = (float*)d_ws;
    float* b    = ws;
    float* p_ws = b + (size_t)GNPTS;
    float* base = p_ws + (size_t)GNPTS;
    float* A_[5], * B_[5];
    size_t lsz[5] = {524288, 131072, 32768, 8192, 2048};
    float* cur = base;
    for (int l = 0; l < 5; ++l) { A_[l] = cur; cur += lsz[l]; }
    for (int l = 0; l < 5; ++l) { B_[l] = cur; cur += lsz[l]; }

    dim3 grdT(GNX / 32, GNY / 32), blkT(256);

    k_front<<<grdT, blkT, 0, stream>>>(u_in, v_in, p_in, sigma,
                                       out_u, out_v, b,
                                       A_[0], A_[1], A_[2], A_[3], A_[4]);

    const float* p_cur = p_in;
    float* p_bufs[2] = { out_p, p_ws };   // it0->out_p, it1->p_ws, ..., it4->out_p
    for (int it = 0; it < 5; ++it) {
        float** rp = (it % 2 == 0) ? A_ : B_;
        float** wp = (it % 2 == 0) ? B_ : A_;
        float* p_next = p_bufs[it % 2];
        int last = (it == 4) ? 1 : 0;
        k_mg<<<grdT, blkT, 0, stream>>>(p_cur, b,
                                        rp[0], rp[1], rp[2], rp[3], rp[4],
                                        p_next,
                                        wp[0], wp[1], wp[2], wp[3], wp[4],
                                        sigma, out_u, out_v, last);
        p_cur = p_next;
    }
}